// Round 4
// baseline (9875.245 us; speedup 1.0000x reference)
//
#include <hip/hip_runtime.h>
#include <hip/hip_bf16.h>

#define T_TOTAL 4096
#define BATCH   64
#define IDIM    128
#define HDIM    128
#define GDIM    512   // 4*H
#define WIN     32    // timesteps per window (T_TOTAL % WIN == 0)

__device__ __forceinline__ float sigmoid_fast(float x) {
    return 1.0f / (1.0f + __expf(-x));
}
__device__ __forceinline__ float tanh_fast(float x) {
    // tanh(x) = 1 - 2/(exp(2x)+1); saturates correctly at +/-inf
    float e = __expf(2.0f * x);
    return 1.0f - 2.0f / (e + 1.0f);
}

// ---------------------------------------------------------------------------
// Fully fused LSTM: one block per batch column, 512 threads = one gate row
// each. W_hh row resident in 128 VGPRs. Per 32-step window: stage x[t] slab
// to LDS, compute input projections (W_ih streamed from L2 in 16-float
// chunks, accumulators fully unrolled in registers), then run 32 recurrent
// steps with h broadcast from LDS. No global scratch (d_ws unused).
// Outputs are FLOAT32 (the reference's output dtype).
// ---------------------------------------------------------------------------
__global__ __launch_bounds__(512, 2)
void lstm_fused(const float* __restrict__ seq,    // [T, B, I]
                const float* __restrict__ w_ih,   // [512, 128]
                const float* __restrict__ w_hh,   // [512, 128]
                const float* __restrict__ b_ih,   // [512]
                const float* __restrict__ b_hh,   // [512]
                float* __restrict__ out_hs,       // [T, B, H]
                float* __restrict__ out_hn,       // [B, H]
                float* __restrict__ out_cn)       // [B, H]
{
    const int b = blockIdx.x;
    const int g = threadIdx.x;

    __shared__ __align__(16) float x_lds[WIN][IDIM];    // 16 KB
    __shared__ __align__(16) float xp_lds[WIN][GDIM];   // 64 KB
    __shared__ __align__(16) float h_lds[HDIM];         // 0.5 KB
    __shared__ __align__(16) float ifgo[GDIM];          // 2 KB

    // W_hh row g into registers (128 VGPRs)
    float whh[HDIM];
    {
        const float4* __restrict__ wv = (const float4*)(w_hh + (size_t)g * HDIM);
        #pragma unroll
        for (int i = 0; i < HDIM / 4; ++i) {
            float4 t = wv[i];
            whh[4*i] = t.x; whh[4*i+1] = t.y; whh[4*i+2] = t.z; whh[4*i+3] = t.w;
        }
    }
    const float bias = b_ih[g] + b_hh[g];

    float c = 0.f;
    if (g < HDIM) h_lds[g] = 0.f;
    __syncthreads();

    for (int t0 = 0; t0 < T_TOTAL; t0 += WIN) {
        // ---- stage x window: 32 steps x 128 floats, coalesced float4 ----
        {
            const int w = g >> 4;       // 0..31: which timestep
            const int j = g & 15;       // 0..15: which float4
            const float4* __restrict__ src =
                (const float4*)(seq + ((size_t)(t0 + w) * BATCH + b) * IDIM);
            float4* dst = (float4*)(&x_lds[w][0]);
            dst[j]      = src[j];
            dst[j + 16] = src[j + 16];
        }
        __syncthreads();

        // ---- input projection for the window ----
        // acc[w] = bias + dot(w_ih[g,:], x[t0+w]); W_ih processed in 8
        // chunks of 16 floats to bound VGPR pressure.
        float acc[WIN];
        #pragma unroll
        for (int w = 0; w < WIN; ++w) acc[w] = bias;

        for (int p = 0; p < 8; ++p) {
            float4 wq[4];
            const float4* __restrict__ wv =
                (const float4*)(w_ih + (size_t)g * IDIM + p * 16);
            #pragma unroll
            for (int i = 0; i < 4; ++i) wq[i] = wv[i];

            #pragma unroll
            for (int w = 0; w < WIN; ++w) {
                const float4* xv = (const float4*)(&x_lds[w][p * 16]);
                float s0 = 0.f, s1 = 0.f, s2 = 0.f, s3 = 0.f;
                #pragma unroll
                for (int i = 0; i < 4; ++i) {
                    float4 x4 = xv[i];
                    s0 += wq[i].x * x4.x;
                    s1 += wq[i].y * x4.y;
                    s2 += wq[i].z * x4.z;
                    s3 += wq[i].w * x4.w;
                }
                acc[w] += (s0 + s1) + (s2 + s3);
            }
        }
        #pragma unroll
        for (int w = 0; w < WIN; ++w) xp_lds[w][g] = acc[w];
        __syncthreads();

        // ---- 32 recurrent steps ----
        for (int w = 0; w < WIN; ++w) {
            float a0 = xp_lds[w][g], a1 = 0.f, a2 = 0.f, a3 = 0.f;
            const float4* hv = (const float4*)h_lds;
            #pragma unroll
            for (int k = 0; k < HDIM / 4; ++k) {
                float4 h4 = hv[k];
                a0 += whh[4*k]   * h4.x;
                a1 += whh[4*k+1] * h4.y;
                a2 += whh[4*k+2] * h4.z;
                a3 += whh[4*k+3] * h4.w;
            }
            ifgo[g] = (a0 + a1) + (a2 + a3);
            __syncthreads();

            if (g < HDIM) {
                float vi = ifgo[g];
                float vf = ifgo[HDIM + g];
                float vg = ifgo[2 * HDIM + g];
                float vo = ifgo[3 * HDIM + g];
                float si = sigmoid_fast(vi);
                float sf = sigmoid_fast(vf);
                float tg = tanh_fast(vg);
                float so = sigmoid_fast(vo);
                c = sf * c + si * tg;
                float h = so * tanh_fast(c);
                h_lds[g] = h;
                out_hs[((size_t)(t0 + w) * BATCH + b) * HDIM + g] = h;
            }
            __syncthreads();
        }
    }

    if (g < HDIM) {
        out_hn[b * HDIM + g] = h_lds[g];
        out_cn[b * HDIM + g] = c;
    }
}

extern "C" void kernel_launch(void* const* d_in, const int* in_sizes, int n_in,
                              void* d_out, int out_size, void* d_ws, size_t ws_size,
                              hipStream_t stream)
{
    const float* seq  = (const float*)d_in[0];
    const float* w_ih = (const float*)d_in[1];
    const float* w_hh = (const float*)d_in[2];
    const float* b_ih = (const float*)d_in[3];
    const float* b_hh = (const float*)d_in[4];

    float* out    = (float*)d_out;
    float* out_hs = out;
    float* out_hn = out + (size_t)T_TOTAL * BATCH * HDIM;
    float* out_cn = out_hn + (size_t)BATCH * HDIM;

    (void)d_ws; (void)ws_size;  // no global scratch used

    lstm_fused<<<BATCH, 512, 0, stream>>>(seq, w_ih, w_hh, b_ih, b_hh,
                                          out_hs, out_hn, out_cn);
}